// Round 10
// baseline (260.215 us; speedup 1.0000x reference)
//
#include <hip/hip_runtime.h>
#include <math.h>

// Problem constants
#define Bn 4
#define Cn 64
#define Np 4096   // 64*64
#define NSPLIT 4
// SCALE * log2(e): folded into all Q pre-scales; attention uses exp2f (native v_exp_f32)
#define SCALE2 0.18033688011112042f

typedef unsigned short ushort_t;
typedef __attribute__((ext_vector_type(4))) float f32x4;
typedef __attribute__((ext_vector_type(8))) short bf16x8;
typedef __attribute__((ext_vector_type(4))) short bf16x4;

__device__ __forceinline__ float gelu_exact(float x) {
    return 0.5f * x * (1.0f + erff(x * 0.70710678118654752440f));
}
__device__ __forceinline__ ushort_t f2bf(float f) {       // RNE float->bf16
    unsigned int u = __float_as_uint(f);
    u += 0x7fffu + ((u >> 16) & 1u);
    return (ushort_t)(u >> 16);
}
__device__ __forceinline__ ushort_t f2bf_tr(float f) {    // truncating (1 VALU)
    return (ushort_t)(__float_as_uint(f) >> 16);
}
__device__ __forceinline__ float bf2f(ushort_t h) {
    return __uint_as_float(((unsigned int)h) << 16);
}
__device__ __forceinline__ void gload_lds16(const ushort_t* g, ushort_t* l) {
    __builtin_amdgcn_global_load_lds(
        (const __attribute__((address_space(1))) void*)g,
        (__attribute__((address_space(3))) void*)l, 16, 0, 0);
}
__device__ __forceinline__ bf16x8 cvt8(const float v[8]) {
    bf16x8 r;
    #pragma unroll
    for (int j = 0; j < 8; ++j) r[j] = (short)f2bf(v[j]);
    return r;
}
// Normal orientation: D[n][o]; acc C: row=n_sub, col=o.
__device__ __forceinline__ void gemm16(const bf16x8 af[2], const float* __restrict__ W,
                                       int l16, int quad, f32x4* acc) {
    #pragma unroll
    for (int cb = 0; cb < 4; ++cb) {
        #pragma unroll
        for (int ks = 0; ks < 2; ++ks) {
            const float* p = W + (cb * 16 + l16) * 64 + ks * 32 + quad * 8;
            float v[8];
            #pragma unroll
            for (int j = 0; j < 8; ++j) v[j] = p[j];
            acc[cb] = __builtin_amdgcn_mfma_f32_16x16x32_bf16(af[ks], cvt8(v), acc[cb], 0, 0, 0);
        }
    }
}
// Transposed orientation: D[o][n]; acc C: row=o_sub, col=n -> ushort4 channel-packed stores.
__device__ __forceinline__ void gemm16T(const bf16x8 af[2], const float* __restrict__ W,
                                        int l16, int quad, f32x4* acc) {
    #pragma unroll
    for (int cb = 0; cb < 4; ++cb) {
        #pragma unroll
        for (int ks = 0; ks < 2; ++ks) {
            const float* p = W + (cb * 16 + l16) * 64 + ks * 32 + quad * 8;
            float v[8];
            #pragma unroll
            for (int j = 0; j < 8; ++j) v[j] = p[j];
            acc[cb] = __builtin_amdgcn_mfma_f32_16x16x32_bf16(cvt8(v), af[ks], acc[cb], 0, 0, 0);
        }
    }
}
__device__ __forceinline__ void aload(const float* xs, int row, int quad, bf16x8 af[2]) {
    #pragma unroll
    for (int ks = 0; ks < 2; ++ks) {
        float v[8];
        #pragma unroll
        for (int j = 0; j < 8; ++j) v[j] = xs[(ks * 32 + quad * 8 + j) * 65 + row];
        af[ks] = cvt8(v);
    }
}
__device__ __forceinline__ void stage_bchw(const float* __restrict__ X, int b, int n0, int t,
                                           float* xs) {
    #pragma unroll
    for (int u = 0; u < 16; ++u) {
        int idx = t + u * 256;
        int c = idx >> 6, nl = idx & 63;
        xs[c * 65 + nl] = X[((size_t)(b * Cn + c)) * Np + n0 + nl];
    }
}
// combine NSPLIT bf16 attention partials * 1/l -> fp32 xs tile
__device__ __forceinline__ void stage_comb(const ushort_t* __restrict__ OpB, const float* linv,
                                           int b, int n0, int t, float* xs) {
    const size_t SS = (size_t)Bn * Np * Cn;
    #pragma unroll
    for (int u = 0; u < 16; ++u) {
        int idx = t + u * 256;
        int nl = idx >> 6, c = idx & 63;
        size_t gi = ((size_t)(b * Np + n0 + nl)) * Cn + c;
        float s = bf2f(OpB[gi]) + bf2f(OpB[SS + gi]) +
                  bf2f(OpB[2 * SS + gi]) + bf2f(OpB[3 * SS + gi]);
        xs[c * 65 + nl] = s * linv[nl];
    }
}
__device__ __forceinline__ void store_bnc_T(ushort_t* __restrict__ Y, int b, int n, int quad,
                                            const f32x4* acc, const float* __restrict__ bias,
                                            float mult) {
    #pragma unroll
    for (int cb = 0; cb < 4; ++cb) {
        int o0 = cb * 16 + quad * 4;
        ushort4 pk;
        pk.x = f2bf((acc[cb][0] + bias[o0 + 0]) * mult);
        pk.y = f2bf((acc[cb][1] + bias[o0 + 1]) * mult);
        pk.z = f2bf((acc[cb][2] + bias[o0 + 2]) * mult);
        pk.w = f2bf((acc[cb][3] + bias[o0 + 3]) * mult);
        *(ushort4*)(Y + ((size_t)(b * Np + n)) * Cn + o0) = pk;
    }
}
__device__ __forceinline__ void store_bchw_bf16(ushort_t* __restrict__ Y, int b, int nb, int l16,
                                                const f32x4* acc, const float* __restrict__ bias) {
    #pragma unroll
    for (int cb = 0; cb < 4; ++cb) {
        int col = cb * 16 + l16;
        float bb = bias[col];
        ushort4 pk;
        pk.x = f2bf(acc[cb][0] + bb); pk.y = f2bf(acc[cb][1] + bb);
        pk.z = f2bf(acc[cb][2] + bb); pk.w = f2bf(acc[cb][3] + bb);
        *(ushort4*)(Y + ((size_t)(b * Cn + col)) * Np + nb) = pk;
    }
}

// ---------------------------------------------------------------- avgpool 2x2 + GAP partials + wcomb
__global__ void avgpool_kernel(const float* __restrict__ x, float* __restrict__ xp,
                               float* __restrict__ gap4k,
                               const float* __restrict__ convh_w, const float* __restrict__ convh_b,
                               const float* __restrict__ sch_pw, const float* __restrict__ sch_pwb,
                               const float* __restrict__ scv_pw, const float* __restrict__ scv_pwb,
                               float* __restrict__ Wc1, float* __restrict__ Wc2,
                               float* __restrict__ bcv) {
    if (blockIdx.x < 4096) {
        int idx = blockIdx.x * 256 + threadIdx.x;
        int j  = idx & 63;
        int i  = (idx >> 6) & 63;
        int bc = idx >> 12;
        const float* p = x + ((size_t)bc * 128 + 2 * i) * 128 + 2 * j;
        float v = 0.25f * (p[0] + p[1] + p[128] + p[129]);
        xp[idx] = v;
        float s = v;
        #pragma unroll
        for (int off = 1; off < 64; off <<= 1) s += __shfl_xor(s, off, 64);
        __shared__ float sm[4];
        if ((threadIdx.x & 63) == 0) sm[threadIdx.x >> 6] = s;
        __syncthreads();
        if (threadIdx.x == 0) gap4k[blockIdx.x] = sm[0] + sm[1] + sm[2] + sm[3];
    } else {
        int g = (blockIdx.x - 4096) * 256 + threadIdx.x;   // 8192 threads
        int sel = g >> 12, idx = g & 4095;
        int o = idx >> 6, c = idx & 63;
        const float* pw = sel ? scv_pw : sch_pw;
        float acc = 0.f;
        #pragma unroll 8
        for (int m = 0; m < 64; ++m) acc += convh_w[o * 64 + m] * pw[m * 64 + c];
        (sel ? Wc2 : Wc1)[idx] = acc * SCALE2;
        if (g < 64) {
            float ab = convh_b[g];
            for (int m = 0; m < 64; ++m) ab += convh_w[g * 64 + m] * (sch_pwb[m] + scv_pwb[m]);
            bcv[g] = ab * SCALE2;
        }
    }
}

// ---------------------------------------------------------------- merged: QKV+Wo (x<64) | dwpair (x>=64)
__global__ __launch_bounds__(256) void qkv_dw_kernel(
    const float* __restrict__ xp, const float* __restrict__ gap4k,
    const float* __restrict__ Wq, const float* __restrict__ bq,
    const float* __restrict__ Wk, const float* __restrict__ bk,
    const float* __restrict__ Wv, const float* __restrict__ bv,
    const float* __restrict__ Wo, const float* __restrict__ bo,
    ushort_t* __restrict__ qb, ushort_t* __restrict__ kb, ushort_t* __restrict__ vb,
    float* __restrict__ xV, ushort_t* __restrict__ xVtb,
    const float* __restrict__ wv5, const float* __restrict__ bv5,
    const float* __restrict__ wh5, const float* __restrict__ bh5,
    ushort_t* __restrict__ gh, ushort_t* __restrict__ gv) {
    int b = blockIdx.y, t = threadIdx.x;
    if (blockIdx.x >= 64) {
        // ---- dwpair: 4 consecutive elems/thread, bf16 outputs
        int part = blockIdx.x - 64;                  // 0..255
        int e = part * 1024 + t * 4;                 // within-batch offset
        size_t base = (size_t)b * (Cn * Np) + e;
        int c = e >> 12, i = (e >> 6) & 63, j = e & 63;
        const float* p = xp + ((size_t)(b * Cn + c)) * Np;
        float accV[4], accH[4];
        #pragma unroll
        for (int k = 0; k < 4; ++k) { accV[k] = bv5[c]; accH[k] = bh5[c]; }
        #pragma unroll
        for (int d = 0; d < 5; ++d) {
            int ii = i + d - 2;
            if (ii >= 0 && ii < 64) {
                #pragma unroll
                for (int k = 0; k < 4; ++k) accV[k] += wv5[c * 5 + d] * p[ii * 64 + j + k];
            }
        }
        #pragma unroll
        for (int k = 0; k < 4; ++k) {
            #pragma unroll
            for (int d = 0; d < 5; ++d) {
                int jj = j + k + d - 2;
                if (jj >= 0 && jj < 64) accH[k] += wh5[c * 5 + d] * p[i * 64 + jj];
            }
        }
        ushort4 ph, pv_;
        ph.x = f2bf(gelu_exact(accV[0])); ph.y = f2bf(gelu_exact(accV[1]));
        ph.z = f2bf(gelu_exact(accV[2])); ph.w = f2bf(gelu_exact(accV[3]));
        pv_.x = f2bf(gelu_exact(accH[0])); pv_.y = f2bf(gelu_exact(accH[1]));
        pv_.z = f2bf(gelu_exact(accH[2])); pv_.w = f2bf(gelu_exact(accH[3]));
        *(ushort4*)(gh + base) = ph;
        *(ushort4*)(gv + base) = pv_;
        return;
    }
    // ---- QKV + Wo
    __shared__ float xs[64 * 65];
    __shared__ float gl[64];
    int n0 = blockIdx.x * 64;
    int wv_ = t >> 6, lane = t & 63, l16 = lane & 15, quad = lane >> 4;
    stage_bchw(xp, b, n0, t, xs);
    if (t < 64) {
        float s = 0.f;
        #pragma unroll
        for (int u = 0; u < 16; ++u) s += gap4k[(b * 64 + t) * 16 + u];
        gl[t] = s * (1.f / 4096.f);
    }
    __syncthreads();
    int row = wv_ * 16 + l16;
    int n   = n0 + wv_ * 16 + l16;
    int nb  = n0 + wv_ * 16 + quad * 4;
    bf16x8 ar[2], ag[2];
    #pragma unroll
    for (int ks = 0; ks < 2; ++ks) {
        float vr[8], vg[8];
        #pragma unroll
        for (int j = 0; j < 8; ++j) {
            int k = ks * 32 + quad * 8 + j;
            float xv = xs[k * 65 + row];
            vr[j] = xv; vg[j] = xv * gl[k];
        }
        ar[ks] = cvt8(vr); ag[ks] = cvt8(vg);
    }
    f32x4 acc[4];
    #pragma unroll
    for (int cb = 0; cb < 4; ++cb) acc[cb] = (f32x4){0.f, 0.f, 0.f, 0.f};
    gemm16T(ag, Wq, l16, quad, acc);
    store_bnc_T(qb, b, n, quad, acc, bq, SCALE2);
    #pragma unroll
    for (int cb = 0; cb < 4; ++cb) acc[cb] = (f32x4){0.f, 0.f, 0.f, 0.f};
    gemm16T(ag, Wk, l16, quad, acc);
    store_bnc_T(kb, b, n, quad, acc, bk, 1.f);
    #pragma unroll
    for (int cb = 0; cb < 4; ++cb) acc[cb] = (f32x4){0.f, 0.f, 0.f, 0.f};
    gemm16(ag, Wv, l16, quad, acc);
    store_bchw_bf16(vb, b, nb, l16, acc, bv);
    #pragma unroll
    for (int cb = 0; cb < 4; ++cb) acc[cb] = (f32x4){0.f, 0.f, 0.f, 0.f};
    gemm16(ar, Wo, l16, quad, acc);
    #pragma unroll
    for (int cb = 0; cb < 4; ++cb) {
        int col = cb * 16 + l16;
        float bb = bo[col];
        ushort4 pk;
        float y0 = acc[cb][0] + bb, y1 = acc[cb][1] + bb, y2 = acc[cb][2] + bb, y3 = acc[cb][3] + bb;
        xV[((size_t)(b * Np + nb + 0)) * Cn + col] = y0;
        xV[((size_t)(b * Np + nb + 1)) * Cn + col] = y1;
        xV[((size_t)(b * Np + nb + 2)) * Cn + col] = y2;
        xV[((size_t)(b * Np + nb + 3)) * Cn + col] = y3;
        pk.x = f2bf(y0); pk.y = f2bf(y1); pk.z = f2bf(y2); pk.w = f2bf(y3);
        *(ushort4*)(xVtb + ((size_t)(b * Cn + col)) * Np + nb) = pk;
    }
}

// ---------------------------------------------------------------- attention body (device)
// 128 q-rows per block (2 q-groups per wave): every K/V LDS fragment feeds TWO MFMAs,
// halving LDS traffic per query (R9 was LDS-pipe-bound). Grid: 32 qt x NSPLIT x B = 512.
__device__ __forceinline__ void attn_body(
    int xblk, int b, const ushort_t* __restrict__ Qb, const ushort_t* __restrict__ Kb,
    const ushort_t* __restrict__ Vtb, ushort_t* __restrict__ OpB, float* __restrict__ Lpart,
    ushort_t* smem) {
    ushort_t* kt0 = smem;            // [2][4096]
    ushort_t* vt0 = smem + 8192;     // [2][4096]
    int split = xblk >> 5;           // 0..3
    int qt    = xblk & 31;
    int n0    = qt * 128;
    int t     = threadIdx.x;         // 0..255
    int wave  = t >> 6, lane = t & 63;
    int l16   = lane & 15, quad = lane >> 4;

    bf16x8 aq[2][2];                 // [qg][ks]
    #pragma unroll
    for (int qg = 0; qg < 2; ++qg) {
        const ushort_t* qp = Qb + ((size_t)(b * Np) + n0 + qg * 64 + wave * 16 + l16) * Cn + quad * 8;
        aq[qg][0] = *(const bf16x8*)(qp);
        aq[qg][1] = *(const bf16x8*)(qp + 32);
    }

    f32x4 oa[2][4];
    float psum[2] = {0.f, 0.f};
    #pragma unroll
    for (int qg = 0; qg < 2; ++qg)
        #pragma unroll
        for (int db = 0; db < 4; ++db) oa[qg][db] = (f32x4){0.f, 0.f, 0.f, 0.f};

    int lrow = lane >> 3;
    int kvbase = split * (Np / NSPLIT);      // 1024 kv per split
    const ushort_t* Kg = Kb + ((size_t)b * Np) * Cn;
    const ushort_t* Vg = Vtb + ((size_t)b * Cn) * Np;

    auto stage = [&](int buf, int k0) {
        int wh = wave & 1;
        if (wave < 2) {
            ushort_t* dst = kt0 + buf * 4096 + wh * 2048;
            #pragma unroll
            for (int u = 0; u < 4; ++u) {
                int r = wh * 32 + u * 8 + lrow;
                int jsw = ((lane & 7) ^ lrow ^ (wh * 4 + u)) & 7;
                gload_lds16(Kg + ((size_t)(k0 + r)) * Cn + jsw * 8, dst + u * 512);
            }
        } else {
            ushort_t* dst = vt0 + buf * 4096 + wh * 2048;
            #pragma unroll
            for (int u = 0; u < 4; ++u) {
                int d = wh * 32 + u * 8 + lrow;
                int jsw = ((lane & 7) ^ lrow ^ (wh * 4 + u)) & 7;
                gload_lds16(Vg + (size_t)d * Np + k0 + jsw * 8, dst + u * 512);
            }
        }
    };
    const int NT = (Np / NSPLIT) / 64;       // 16
    stage(0, kvbase);
    __syncthreads();

    for (int m = 0; m < NT; ++m) {
        int cur = m & 1;
        if (m + 1 < NT) stage(1 - cur, kvbase + (m + 1) * 64);
        const ushort_t* ktc = kt0 + cur * 4096;
        const ushort_t* vtc = vt0 + cur * 4096;

        // S^T = K Q for both q-groups; each bk load feeds 4 MFMAs (2 qg x 2 ks)
        f32x4 sa[2][4];
        #pragma unroll
        for (int qg = 0; qg < 2; ++qg)
            #pragma unroll
            for (int cb = 0; cb < 4; ++cb) sa[qg][cb] = (f32x4){0.f, 0.f, 0.f, 0.f};
        #pragma unroll
        for (int cb = 0; cb < 4; ++cb) {
            int key = ((l16 & 7) ^ (cb * 2 + (l16 >> 3))) & 7;
            const ushort_t* krow = ktc + (cb * 16 + l16) * 64;
            bf16x8 bk0 = *(const bf16x8*)(krow + ((quad    ) ^ key) * 8);
            bf16x8 bk1 = *(const bf16x8*)(krow + ((quad + 4) ^ key) * 8);
            #pragma unroll
            for (int qg = 0; qg < 2; ++qg) {
                sa[qg][cb] = __builtin_amdgcn_mfma_f32_16x16x32_bf16(bk0, aq[qg][0], sa[qg][cb], 0, 0, 0);
                sa[qg][cb] = __builtin_amdgcn_mfma_f32_16x16x32_bf16(bk1, aq[qg][1], sa[qg][cb], 0, 0, 0);
            }
        }
        // p = 2^s; truncating bf16 pack straight into PV B-fragments
        bf16x4 pb[2][4];
        #pragma unroll
        for (int qg = 0; qg < 2; ++qg) {
            #pragma unroll
            for (int cb = 0; cb < 4; ++cb) {
                float p0 = exp2f(sa[qg][cb][0]), p1 = exp2f(sa[qg][cb][1]);
                float p2 = exp2f(sa[qg][cb][2]), p3 = exp2f(sa[qg][cb][3]);
                psum[qg] += (p0 + p1) + (p2 + p3);
                bf16x4 pk;
                pk[0] = (short)f2bf_tr(p0); pk[1] = (short)f2bf_tr(p1);
                pk[2] = (short)f2bf_tr(p2); pk[3] = (short)f2bf_tr(p3);
                pb[qg][cb] = pk;
            }
        }
        // O^T += V^T P^T ; each va load feeds 2 MFMAs (both q-groups)
        #pragma unroll
        for (int kc = 0; kc < 4; ++kc) {
            #pragma unroll
            for (int db = 0; db < 4; ++db) {
                int d = db * 16 + l16;
                int key = ((l16 & 7) ^ (db * 2 + (l16 >> 3))) & 7;
                int phys = (kc * 2 + (quad >> 1)) ^ key;
                const ushort_t* va = vtc + d * 64 + phys * 8 + (quad & 1) * 4;
                bf16x4 av = *(const bf16x4*)va;
                oa[0][db] = __builtin_amdgcn_mfma_f32_16x16x16bf16_1k(av, pb[0][kc], oa[0][db], 0, 0, 0);
                oa[1][db] = __builtin_amdgcn_mfma_f32_16x16x16bf16_1k(av, pb[1][kc], oa[1][db], 0, 0, 0);
            }
        }
        __syncthreads();
    }
    size_t obase = ((size_t)(split * Bn + b)) * Np;
    #pragma unroll
    for (int qg = 0; qg < 2; ++qg) {
        float s = psum[qg];
        s += __shfl_xor(s, 16, 64);
        s += __shfl_xor(s, 32, 64);
        int n = n0 + qg * 64 + wave * 16 + l16;
        if (quad == 0) Lpart[obase + n] = s;
        #pragma unroll
        for (int db = 0; db < 4; ++db) {
            ushort4 pk;
            pk.x = f2bf(oa[qg][db][0]); pk.y = f2bf(oa[qg][db][1]);
            pk.z = f2bf(oa[qg][db][2]); pk.w = f2bf(oa[qg][db][3]);
            *(ushort4*)(OpB + (obase + n) * Cn + db * 16 + quad * 4) = pk;
        }
    }
}

// hpg body: bf16 gh/gv staged [n][c] stride 72, combined 1x1 (SCALE2 folded) -> xQb
__device__ __forceinline__ void hpg_body(
    int tile, int b, const ushort_t* __restrict__ gh, const ushort_t* __restrict__ gv,
    const float* __restrict__ Wc1, const float* __restrict__ Wc2, const float* __restrict__ bcv,
    ushort_t* __restrict__ xQb, ushort_t* smem) {
    ushort_t* xs1 = smem;            // 64 x 72
    ushort_t* xs2 = smem + 4608;
    int n0 = tile * 64, t = threadIdx.x;
    int wv_ = t >> 6, lane = t & 63, l16 = lane & 15, quad = lane >> 4;
    #pragma unroll
    for (int u = 0; u < 4; ++u) {
        int lin = u * 256 + t;
        int c = lin >> 4, nl4 = (lin & 15) * 4;
        size_t gi = ((size_t)(b * Cn + c)) * Np + n0 + nl4;
        ushort4 g1 = *(const ushort4*)(gh + gi);
        ushort4 g2 = *(const ushort4*)(gv + gi);
        xs1[(nl4 + 0) * 72 + c] = g1.x; xs1[(nl4 + 1) * 72 + c] = g1.y;
        xs1[(nl4 + 2) * 72 + c] = g1.z; xs1[(nl4 + 3) * 72 + c] = g1.w;
        xs2[(nl4 + 0) * 72 + c] = g2.x; xs2[(nl4 + 1) * 72 + c] = g2.y;
        xs2[(nl4 + 2) * 72 + c] = g2.z; xs2[(nl4 + 3) * 72 + c] = g2.w;
    }
    __syncthreads();
    int row = wv_ * 16 + l16;
    bf16x8 a1[2], a2[2];
    #pragma unroll
    for (int ks = 0; ks < 2; ++ks) {
        a1[ks] = *(const bf16x8*)(xs1 + row * 72 + ks * 32 + quad * 8);
        a2[ks] = *(const bf16x8*)(xs2 + row * 72 + ks * 32 + quad * 8);
    }
    f32x4 acc[4];
    #pragma unroll
    for (int cb = 0; cb < 4; ++cb) acc[cb] = (f32x4){0.f, 0.f, 0.f, 0.f};
    gemm16T(a1, Wc1, l16, quad, acc);
    gemm16T(a2, Wc2, l16, quad, acc);
    store_bnc_T(xQb, b, n0 + wv_ * 16 + l16, quad, acc, bcv, 1.f);
}

// merged launch: x<128 -> attention ; x>=128 -> hpg tile (x-128)
__global__ __launch_bounds__(256, 2) void attn_hpg_kernel(
    const ushort_t* __restrict__ Qb, const ushort_t* __restrict__ Kb,
    const ushort_t* __restrict__ Vtb, ushort_t* __restrict__ OpB, float* __restrict__ Lpart,
    const ushort_t* __restrict__ gh, const ushort_t* __restrict__ gv,
    const float* __restrict__ Wc1, const float* __restrict__ Wc2,
    const float* __restrict__ bcv, ushort_t* __restrict__ xQb) {
    __shared__ ushort_t smem[16384];   // attn: 2x(4096+4096); hpg: 2x4608
    int b = blockIdx.y;
    if (blockIdx.x < 128)
        attn_body(blockIdx.x, b, Qb, Kb, Vtb, OpB, Lpart, smem);
    else
        hpg_body(blockIdx.x - 128, b, gh, gv, Wc1, Wc2, bcv, xQb, smem);
}

// ---------------------------------------------------------------- combine(attn1)+Wl -> xKb
__global__ __launch_bounds__(256) void wl_mfma(
    const ushort_t* __restrict__ OpB, const float* __restrict__ Lp,
    const float* __restrict__ Wl, const float* __restrict__ bl, ushort_t* __restrict__ xKb) {
    __shared__ float xs[64 * 65];
    __shared__ float linv[64];
    int b = blockIdx.y, n0 = blockIdx.x * 64, t = threadIdx.x;
    int wv_ = t >> 6, lane = t & 63, l16 = lane & 15, quad = lane >> 4;
    if (t < 64) {
        size_t li = (size_t)b * Np + n0 + t;
        const size_t LS = (size_t)Bn * Np;
        linv[t] = 1.f / (Lp[li] + Lp[LS + li] + Lp[2 * LS + li] + Lp[3 * LS + li]);
    }
    __syncthreads();
    stage_comb(OpB, linv, b, n0, t, xs);
    __syncthreads();
    bf16x8 af[2];
    aload(xs, wv_ * 16 + l16, quad, af);
    f32x4 acc[4];
    #pragma unroll
    for (int cb = 0; cb < 4; ++cb) acc[cb] = (f32x4){0.f, 0.f, 0.f, 0.f};
    gemm16T(af, Wl, l16, quad, acc);
    store_bnc_T(xKb, b, n0 + wv_ * 16 + l16, quad, acc, bl, 1.f);
}

// ---------------------------------------------------------------- combine(attn2)+Wp+res+LayerNorm -> BCHW
__global__ __launch_bounds__(256) void linln_mfma(
    const ushort_t* __restrict__ OpB, const float* __restrict__ Lp,
    const float* __restrict__ Wp, const float* __restrict__ bp,
    const float* __restrict__ xV, const float* __restrict__ g, const float* __restrict__ beta,
    float* __restrict__ out) {
    __shared__ float xs[64 * 65];
    __shared__ float linv[64];
    int b = blockIdx.y, n0 = blockIdx.x * 64, t = threadIdx.x;
    int wv_ = t >> 6, lane = t & 63, l16 = lane & 15, quad = lane >> 4;
    if (t < 64) {
        size_t li = (size_t)b * Np + n0 + t;
        const size_t LS = (size_t)Bn * Np;
        linv[t] = 1.f / (Lp[li] + Lp[LS + li] + Lp[2 * LS + li] + Lp[3 * LS + li]);
    }
    __syncthreads();
    stage_comb(OpB, linv, b, n0, t, xs);
    __syncthreads();
    bf16x8 af[2];
    aload(xs, wv_ * 16 + l16, quad, af);
    f32x4 acc[4];
    #pragma unroll
    for (int cb = 0; cb < 4; ++cb) acc[cb] = (f32x4){0.f, 0.f, 0.f, 0.f};
    gemm16(af, Wp, l16, quad, acc);
    int nb = n0 + wv_ * 16 + quad * 4;
    float vals[4][4], gc[4], bec[4];
    #pragma unroll
    for (int cb = 0; cb < 4; ++cb) {
        int col = cb * 16 + l16;
        float bb = bp[col];
        gc[cb] = g[col]; bec[cb] = beta[col];
        #pragma unroll
        for (int r = 0; r < 4; ++r)
            vals[cb][r] = acc[cb][r] + bb + xV[((size_t)(b * Np + nb + r)) * Cn + col];
    }
    f32x4 yn[4];
    #pragma unroll
    for (int r = 0; r < 4; ++r) {
        float s = 0.f, s2 = 0.f;
        #pragma unroll
        for (int cb = 0; cb < 4; ++cb) { s += vals[cb][r]; s2 += vals[cb][r] * vals[cb][r]; }
        #pragma unroll
        for (int off = 1; off < 16; off <<= 1) {
            s  += __shfl_xor(s, off, 64);
            s2 += __shfl_xor(s2, off, 64);
        }
        float mu  = s * (1.f / 64.f);
        float var = s2 * (1.f / 64.f) - mu * mu;
        float ivs = rsqrtf(var + 1e-5f);
        #pragma unroll
        for (int cb = 0; cb < 4; ++cb)
            yn[cb][r] = (vals[cb][r] - mu) * ivs * gc[cb] + bec[cb];
    }
    #pragma unroll
    for (int cb = 0; cb < 4; ++cb)
        *(f32x4*)(out + ((size_t)(b * Cn + cb * 16 + l16)) * Np + nb) = yn[cb];
}

// ---------------------------------------------------------------- fused dw3x3+GELU (halo-staged) + 1x1 + residual
__global__ __launch_bounds__(256) void dsc_fused(
    const float* __restrict__ pn, const float* __restrict__ dw, const float* __restrict__ dwb,
    const float* __restrict__ W, const float* __restrict__ bias, float* __restrict__ out) {
    __shared__ float halo[3 * 4096];   // [r][c][j] — each input row staged ONCE
    __shared__ float xs[64 * 65];      // conv+gelu result tile [c][j]
    int b = blockIdx.y, i = blockIdx.x, n0 = i * 64, t = threadIdx.x;
    int wv_ = t >> 6, lane = t & 63, l16 = lane & 15, quad = lane >> 4;
    #pragma unroll
    for (int u = 0; u < 48; ++u) {     // 3*64*64 / 256
        int lin = t + u * 256;
        int r = lin >> 12, rest = lin & 4095;
        int c = rest >> 6, j = rest & 63;
        int ri = i - 1 + r;
        halo[lin] = (ri >= 0 && ri < 64)
            ? pn[((size_t)(b * Cn + c)) * Np + ri * 64 + j] : 0.f;
    }
    __syncthreads();
    #pragma unroll
    for (int u = 0; u < 16; ++u) {
        int idx = t + u * 256;
        int c = idx >> 6, j = idx & 63;
        const float* hc = halo + c * 64;
        float acc = dwb[c];
        #pragma unroll
        for (int dy = 0; dy < 3; ++dy) {
            #pragma unroll
            for (int dx = 0; dx < 3; ++dx) {
                int jj = j + dx - 1;
                if (jj >= 0 && jj < 64) acc += dw[c * 9 + dy * 3 + dx] * hc[dy * 4096 + jj];
            }
        }
        xs[c * 65 + j] = gelu_exact(acc);
    }
    __syncthreads();
    bf16x8 af[2];
    aload(xs, wv_ * 16 + l16, quad, af);
    f32x4 acc[4];
    #pragma unroll
    for (int cb = 0; cb < 4; ++cb) acc[cb] = (f32x4){0.f, 0.f, 0.f, 0.f};
    gemm16(af, W, l16, quad, acc);
    int nb = n0 + wv_ * 16 + quad * 4;
    #pragma unroll
    for (int cb = 0; cb < 4; ++cb) {
        int col = cb * 16 + l16;
        float bb = bias[col];
        size_t oi = ((size_t)(b * Cn + col)) * Np + nb;
        f32x4 rv = *(const f32x4*)(pn + oi);
        f32x4 v4;
        #pragma unroll
        for (int r = 0; r < 4; ++r) v4[r] = acc[cb][r] + bb + rv[r];
        *(f32x4*)(out + oi) = v4;
    }
}

// ---------------------------------------------------------------- bilinear x2 upsample (float4 stores)
__global__ void upsample_kernel(const float* __restrict__ in, float* __restrict__ out) {
    int idx = blockIdx.x * 256 + threadIdx.x;   // 1,048,576 threads, 4 px each
    int x4 = (idx & 31) * 4;
    int y  = (idx >> 5) & 127;
    int bc = idx >> 12;
    float sy = y * (63.f / 127.f);
    int y0 = (int)sy;
    float fy = sy - y0;
    int y1 = min(y0 + 1, 63);
    const float* p0 = in + (size_t)bc * Np + y0 * 64;
    const float* p1 = in + (size_t)bc * Np + y1 * 64;
    f32x4 o;
    #pragma unroll
    for (int k = 0; k < 4; ++k) {
        int x = x4 + k;
        float sx = x * (63.f / 127.f);
        int x0 = (int)sx;
        float fx = sx - x0;
        int x1 = min(x0 + 1, 63);
        float r0 = p0[x0] * (1.f - fx) + p0[x1] * fx;
        float r1 = p1[x0] * (1.f - fx) + p1[x1] * fx;
        o[k] = r0 * (1.f - fy) + r1 * fy;
    }
    *(f32x4*)(out + ((size_t)bc << 14) + y * 128 + x4) = o;
}

// ----------------------------------------------------------------
extern "C" void kernel_launch(void* const* d_in, const int* in_sizes, int n_in,
                              void* d_out, int out_size, void* d_ws, size_t ws_size,
                              hipStream_t stream) {
    const float* x       = (const float*)d_in[0];
    const float* Wq      = (const float*)d_in[1];
    const float* bq      = (const float*)d_in[2];
    const float* Wk      = (const float*)d_in[3];
    const float* bk      = (const float*)d_in[4];
    const float* Wv      = (const float*)d_in[5];
    const float* bv      = (const float*)d_in[6];
    const float* Wl      = (const float*)d_in[7];
    const float* bl      = (const float*)d_in[8];
    const float* Wo      = (const float*)d_in[9];
    const float* bo      = (const float*)d_in[10];
    const float* Wp      = (const float*)d_in[11];
    const float* bp      = (const float*)d_in[12];
    const float* sch_dw  = (const float*)d_in[13];
    const float* sch_dwb = (const float*)d_in[14];
    const float* sch_pw  = (const float*)d_in[15];
    const float* sch_pwb = (const float*)d_in[16];
    const float* scv_dw  = (const float*)d_in[17];
    const float* scv_dwb = (const float*)d_in[18];
    const float* scv_pw  = (const float*)d_in[19];
    const float* scv_pwb = (const float*)d_in[20];
    const float* convh_w = (const float*)d_in[21];
    const float* convh_b = (const float*)d_in[22];
    const float* dsc_dw  = (const float*)d_in[23];
    const float* dsc_dwb = (const float*)d_in[24];
    const float* dsc_pw  = (const float*)d_in[25];
    const float* dsc_pwb = (const float*)d_in[26];
    const float* ln_g    = (const float*)d_in[27];
    const float* ln_b    = (const float*)d_in[28];

    float* ws = (float*)d_ws;
    const size_t SZ = (size_t)Bn * Np * Cn;   // 1,048,576 elements
    float* xp   = ws;                          // pooled BCHW; later p_norm
    float* xV   = ws + SZ;                     // BNC fp32
    ushort_t* ghb = (ushort_t*)(ws + 2 * SZ);  // bf16 gh/gv (floats 2SZ..3SZ)
    ushort_t* gh  = ghb;
    ushort_t* gv  = ghb + SZ;
    float* f2   = ws + 2 * SZ;                 // dsc out (reuses gh/gv region later)
    ushort_t* bws  = (ushort_t*)(ws + 3 * SZ); // floats 3SZ..6SZ
    ushort_t* qb   = bws;
    ushort_t* kb_  = bws + SZ;
    ushort_t* vb   = bws + 2 * SZ;             // bf16 BCHW (V^T)
    ushort_t* xKb  = bws + 3 * SZ;
    ushort_t* xVtb = bws + 4 * SZ;             // bf16 BCHW (V^T)
    ushort_t* xQb  = bws + 5 * SZ;
    ushort_t* OpB  = (ushort_t*)(ws + 6 * SZ); // bf16 partials, 4 x SZ ushorts
    float* gap4k  = ws + 8 * SZ;                        // 4096
    float* Lpart  = gap4k + 4096;                       // NSPLIT*Bn*Np = 65536
    float* Wc1  = Lpart + (size_t)NSPLIT * Bn * Np;     // 4096
    float* Wc2  = Wc1 + 4096;                           // 4096
    float* bcv  = Wc2 + 4096;                           // 64

    dim3 g64(64, Bn);

    // 1) avgpool + GAP partials + weight combine
    avgpool_kernel<<<4096 + 32, 256, 0, stream>>>(x, xp, gap4k,
                                                  convh_w, convh_b, sch_pw, sch_pwb,
                                                  scv_pw, scv_pwb, Wc1, Wc2, bcv);
    // 2) qkv(+Wo) merged with dwpair (bf16 gh/gv)
    qkv_dw_kernel<<<dim3(64 + 256, Bn), 256, 0, stream>>>(
        xp, gap4k, Wq, bq, Wk, bk, Wv, bv, Wo, bo,
        qb, kb_, vb, xV, xVtb, sch_dw, sch_dwb, scv_dw, scv_dwb, gh, gv);
    // 3) attention 1 (128 q/block) merged with hpg (x_Q)
    attn_hpg_kernel<<<dim3(128 + 64, Bn), 256, 0, stream>>>(
        qb, kb_, vb, OpB, Lpart, gh, gv, Wc1, Wc2, bcv, xQb);
    // 4) x_K = linear(combine(attn1), Wl)
    wl_mfma<<<g64, 256, 0, stream>>>(OpB, Lpart, Wl, bl, xKb);
    // 5) attention 2
    attn_hpg_kernel<<<dim3(128, Bn), 256, 0, stream>>>(
        xQb, xKb, xVtb, OpB, Lpart, gh, gv, Wc1, Wc2, bcv, xQb);
    // 6) prompt = linear(combine, Wp) + x_V ; LN ; -> BCHW (xp reused as p_norm)
    linln_mfma<<<g64, 256, 0, stream>>>(OpB, Lpart, Wp, bp, xV, ln_g, ln_b, xp);
    // 7) dsc: halo-staged dw3x3+gelu + 1x1 + residual (fused)
    dsc_fused<<<g64, 256, 0, stream>>>(xp, dsc_dw, dsc_dwb, dsc_pw, dsc_pwb, f2);
    // 8) bilinear x2
    upsample_kernel<<<4096, 256, 0, stream>>>(f2, (float*)d_out);
}